// Round 1
// baseline (511.672 us; speedup 1.0000x reference)
//
#include <hip/hip_runtime.h>

#define T_SEQ 2048
#define DM    2048
#define NH    16
#define HD    128
#define NROW  4096   // B*T

typedef __attribute__((ext_vector_type(8))) short short8;
typedef __attribute__((ext_vector_type(4))) float f32x4;

static __device__ __forceinline__ float bf2f(unsigned short h) {
    unsigned int u = ((unsigned int)h) << 16;
    return __builtin_bit_cast(float, u);
}
static __device__ __forceinline__ unsigned short f2bf(float f) {
    unsigned int u = __builtin_bit_cast(unsigned int, f);
    u += 0x7FFFu + ((u >> 16) & 1u);
    return (unsigned short)(u >> 16);
}

typedef __attribute__((address_space(1))) const unsigned int gas_uint;
typedef __attribute__((address_space(3))) unsigned int las_uint;

static __device__ __forceinline__ void load_lds16(const void* g, void* l) {
    __builtin_amdgcn_global_load_lds((gas_uint*)g, (las_uint*)l, 16, 0, 0);
}

static __device__ __forceinline__ f32x4 mfma_bf16(short8 a, short8 b, f32x4 c) {
    return __builtin_amdgcn_mfma_f32_16x16x32_bf16(a, b, c, 0, 0, 0);
}

// ---------------- cast x -> bf16 ----------------
__global__ __launch_bounds__(256) void k_cast(const float* __restrict__ x,
                                              unsigned short* __restrict__ xb, int n) {
    int idx = (blockIdx.x * 256 + threadIdx.x) * 4;
    if (idx >= n) return;
    float4 v = *(const float4*)(x + idx);
    ushort4 o;
    o.x = f2bf(v.x); o.y = f2bf(v.y); o.z = f2bf(v.z); o.w = f2bf(v.w);
    *(ushort4*)(xb + idx) = o;
}

// ---------------- transpose+cast weights: W[k][n] f32 -> Wt[n][k] bf16 ----------------
__global__ __launch_bounds__(256) void k_transpose(const float* __restrict__ w0, const float* __restrict__ w1,
                                                   const float* __restrict__ w2, const float* __restrict__ w3,
                                                   unsigned short* __restrict__ t0, unsigned short* __restrict__ t1,
                                                   unsigned short* __restrict__ t2, unsigned short* __restrict__ t3) {
    __shared__ float tile[32][33];
    int z = blockIdx.z;
    const float* W = (z == 0) ? w0 : (z == 1) ? w1 : (z == 2) ? w2 : w3;
    unsigned short* Wt = (z == 0) ? t0 : (z == 1) ? t1 : (z == 2) ? t2 : t3;
    int bx = blockIdx.x * 32;  // n base
    int by = blockIdx.y * 32;  // k base
    int tx = threadIdx.x, ty = threadIdx.y;
#pragma unroll
    for (int i = 0; i < 4; ++i)
        tile[ty + i * 8][tx] = W[(size_t)(by + ty + i * 8) * DM + bx + tx];
    __syncthreads();
#pragma unroll
    for (int i = 0; i < 4; ++i)
        Wt[(size_t)(bx + ty + i * 8) * DM + by + tx] = f2bf(tile[tx][ty + i * 8]);
}

// ---------------- 128x128 GEMM, A[M][K] bf16 @ Bt[N][K] bf16 -> C[M][N] ----------------
template <bool FOUT>
static __device__ __forceinline__ void gemm_body(const unsigned short* __restrict__ A,
                                                 const unsigned short* __restrict__ Bt,
                                                 unsigned short* __restrict__ Cb,
                                                 float* __restrict__ Cf) {
    __shared__ unsigned short As[128 * 64];
    __shared__ unsigned short Bs[128 * 64];
    const int tid = threadIdx.x;
    const int w = tid >> 6, lane = tid & 63;
    const int col = lane & 15, quad = lane >> 4;
    const int wm = w >> 1, wn = w & 1;
    const size_t m0 = (size_t)blockIdx.y * 128;
    const size_t n0 = (size_t)blockIdx.x * 128;

    f32x4 acc[4][4];
#pragma unroll
    for (int i = 0; i < 4; ++i)
#pragma unroll
        for (int j = 0; j < 4; ++j)
            acc[i][j] = (f32x4){0.f, 0.f, 0.f, 0.f};

    const int lrow = lane >> 3;                 // 0..7 row within 8-row chunk
    const int gcol = ((lane & 7) ^ lrow) * 8;   // XOR-swizzled logical col (elems)

    for (int k0 = 0; k0 < DM; k0 += 64) {
#pragma unroll
        for (int c = w; c < 16; c += 4) {
            load_lds16(A + (m0 + c * 8 + lrow) * DM + k0 + gcol, &As[c * 512]);
            load_lds16(Bt + (n0 + c * 8 + lrow) * DM + k0 + gcol, &Bs[c * 512]);
        }
        __syncthreads();
#pragma unroll
        for (int ks = 0; ks < 2; ++ks) {
            short8 af[4], bf[4];
            int g = ks * 4 + quad;
#pragma unroll
            for (int mt = 0; mt < 4; ++mt) {
                int r = wm * 64 + mt * 16 + col;
                af[mt] = *(const short8*)&As[r * 64 + ((g ^ (r & 7)) * 8)];
            }
#pragma unroll
            for (int nt = 0; nt < 4; ++nt) {
                int r = wn * 64 + nt * 16 + col;
                bf[nt] = *(const short8*)&Bs[r * 64 + ((g ^ (r & 7)) * 8)];
            }
#pragma unroll
            for (int mt = 0; mt < 4; ++mt)
#pragma unroll
                for (int nt = 0; nt < 4; ++nt)
                    acc[mt][nt] = mfma_bf16(af[mt], bf[nt], acc[mt][nt]);
        }
        __syncthreads();
    }
#pragma unroll
    for (int mt = 0; mt < 4; ++mt)
#pragma unroll
        for (int nt = 0; nt < 4; ++nt)
#pragma unroll
            for (int reg = 0; reg < 4; ++reg) {
                size_t r = m0 + wm * 64 + mt * 16 + quad * 4 + reg;
                size_t c = n0 + wn * 64 + nt * 16 + col;
                if (FOUT) Cf[r * DM + c] = acc[mt][nt][reg];
                else      Cb[r * DM + c] = f2bf(acc[mt][nt][reg]);
            }
}

__global__ __launch_bounds__(256) void k_gemm_qkv(const unsigned short* __restrict__ xb,
                                                  const unsigned short* __restrict__ wtq,
                                                  const unsigned short* __restrict__ wtk,
                                                  const unsigned short* __restrict__ wtv,
                                                  unsigned short* __restrict__ qb,
                                                  unsigned short* __restrict__ kb,
                                                  unsigned short* __restrict__ vb) {
    int z = blockIdx.z;
    const unsigned short* Bt = (z == 0) ? wtq : (z == 1) ? wtk : wtv;
    unsigned short* C = (z == 0) ? qb : (z == 1) ? kb : vb;
    gemm_body<false>(xb, Bt, C, nullptr);
}

__global__ __launch_bounds__(256) void k_gemm_out(const unsigned short* __restrict__ ob,
                                                  const unsigned short* __restrict__ wto,
                                                  float* __restrict__ out) {
    gemm_body<true>(ob, wto, nullptr, out);
}

// ---------------- RoPE in place on Q,K: [B*T][H*D] bf16 ----------------
__global__ __launch_bounds__(256) void k_rope(unsigned short* __restrict__ Q,
                                              unsigned short* __restrict__ K,
                                              const float* __restrict__ cosp,
                                              const float* __restrict__ sinp) {
    int idx = blockIdx.x * 256 + threadIdx.x;      // [0, 4096*16*64)
    int d = idx & 63;
    int h = (idx >> 6) & 15;
    int row = idx >> 10;
    int t = row & (T_SEQ - 1);
    float c = cosp[t * 64 + d];
    float s = sinp[t * 64 + d];
    size_t base = (size_t)row * DM + h * HD + d;
    float q1 = bf2f(Q[base]), q2 = bf2f(Q[base + 64]);
    Q[base]      = f2bf(q1 * c - q2 * s);
    Q[base + 64] = f2bf(q1 * s + q2 * c);
    float k1 = bf2f(K[base]), k2 = bf2f(K[base + 64]);
    K[base]      = f2bf(k1 * c - k2 * s);
    K[base + 64] = f2bf(k1 * s + k2 * c);
}

// ---------------- causal flash attention ----------------
// grid (T/64, H, B), block 256 (4 waves). Wave w -> queries q0+w*16 .. +16.
__global__ __launch_bounds__(256) void k_flash(const unsigned short* __restrict__ Q,
                                               const unsigned short* __restrict__ K,
                                               const unsigned short* __restrict__ V,
                                               unsigned short* __restrict__ O) {
    __shared__ unsigned short Ks[64 * 128];
    __shared__ unsigned short Vt[128 * 64];
    __shared__ unsigned short Ps[4 * 16 * 72];
    const int tid = threadIdx.x;
    const int w = tid >> 6, lane = tid & 63;
    const int col = lane & 15, quad = lane >> 4;
    const int bx = blockIdx.x, h = blockIdx.y, b = blockIdx.z;
    const int q0 = bx * 64;
    const float scale = 0.08838834764831845f;  // 1/sqrt(128)

    const size_t rowbase = ((size_t)b * T_SEQ) * DM + (size_t)h * HD;

    short8 qf[4];
    {
        const unsigned short* qp = Q + rowbase + (size_t)(q0 + w * 16 + col) * DM;
#pragma unroll
        for (int ks = 0; ks < 4; ++ks)
            qf[ks] = *(const short8*)(qp + ks * 32 + quad * 8);
    }

    f32x4 o[8];
#pragma unroll
    for (int i = 0; i < 8; ++i) o[i] = (f32x4){0.f, 0.f, 0.f, 0.f};
    float m_i[4], l_i[4];
#pragma unroll
    for (int r = 0; r < 4; ++r) { m_i[r] = -1e30f; l_i[r] = 0.f; }

    for (int kt = 0; kt <= bx; ++kt) {
        const int k0 = kt * 64;
        __syncthreads();  // protect Ks/Vt reuse across iterations
        // stage K tile [64][128] with XOR swizzle (16 groups/row)
#pragma unroll
        for (int c = w; c < 16; c += 4) {
            int key = c * 4 + (lane >> 4);
            int gl = (lane & 15) ^ (key & 7);
            load_lds16(K + rowbase + (size_t)(k0 + key) * DM + gl * 8, &Ks[c * 512]);
        }
        // stage V transposed: Vt[d][key], 8 groups/row, XOR swizzle
#pragma unroll
        for (int it = 0; it < 4; ++it) {
            int id = tid + it * 256;
            int key = id & 63;
            int d0 = (id >> 6) * 8;
            short8 v = *(const short8*)(V + rowbase + (size_t)(k0 + key) * DM + d0);
            int gl = key >> 3;
#pragma unroll
            for (int i = 0; i < 8; ++i) {
                int d = d0 + i;
                Vt[d * 64 + ((gl ^ (d & 7)) * 8) + (key & 7)] = (unsigned short)v[i];
            }
        }
        __syncthreads();

        // S = Q K^T  (4 key-subtiles of 16)
        f32x4 s[4];
#pragma unroll
        for (int i = 0; i < 4; ++i) s[i] = (f32x4){0.f, 0.f, 0.f, 0.f};
#pragma unroll
        for (int ks = 0; ks < 4; ++ks) {
            int g = ks * 4 + quad;
#pragma unroll
            for (int nt = 0; nt < 4; ++nt) {
                int key = nt * 16 + col;
                short8 bf = *(const short8*)&Ks[key * 128 + ((g ^ (key & 7)) * 8)];
                s[nt] = mfma_bf16(qf[ks], bf, s[nt]);
            }
        }

        const bool maskt = (kt == bx);
#pragma unroll
        for (int reg = 0; reg < 4; ++reg) {
            float mx = -1e30f;
#pragma unroll
            for (int nt = 0; nt < 4; ++nt) {
                float v = s[nt][reg] * scale;
                if (maskt) {
                    int kg = k0 + nt * 16 + col;
                    int qg = q0 + w * 16 + quad * 4 + reg;
                    if (kg > qg) v = -1e30f;
                }
                s[nt][reg] = v;
                mx = fmaxf(mx, v);
            }
            mx = fmaxf(mx, __shfl_xor(mx, 1));
            mx = fmaxf(mx, __shfl_xor(mx, 2));
            mx = fmaxf(mx, __shfl_xor(mx, 4));
            mx = fmaxf(mx, __shfl_xor(mx, 8));
            float mnew = fmaxf(m_i[reg], mx);
            float alpha = __expf(m_i[reg] - mnew);
            m_i[reg] = mnew;
            float sum = 0.f;
#pragma unroll
            for (int nt = 0; nt < 4; ++nt) {
                float p = __expf(s[nt][reg] - mnew);
                s[nt][reg] = p;
                sum += p;
            }
            sum += __shfl_xor(sum, 1);
            sum += __shfl_xor(sum, 2);
            sum += __shfl_xor(sum, 4);
            sum += __shfl_xor(sum, 8);
            l_i[reg] = l_i[reg] * alpha + sum;
#pragma unroll
            for (int nt2 = 0; nt2 < 8; ++nt2) o[nt2][reg] *= alpha;
            // P tile row -> per-wave LDS (C-layout -> A-layout transform)
            int prow = w * 16 + quad * 4 + reg;
#pragma unroll
            for (int nt = 0; nt < 4; ++nt)
                Ps[prow * 72 + nt * 16 + col] = f2bf(s[nt][reg]);
        }

        // O += P @ V
#pragma unroll
        for (int ks2 = 0; ks2 < 2; ++ks2) {
            short8 a = *(const short8*)&Ps[(w * 16 + col) * 72 + ks2 * 32 + quad * 8];
            int g = ks2 * 4 + quad;
#pragma unroll
            for (int nt2 = 0; nt2 < 8; ++nt2) {
                int d = nt2 * 16 + col;
                short8 bf = *(const short8*)&Vt[d * 64 + ((g ^ (d & 7)) * 8)];
                o[nt2] = mfma_bf16(a, bf, o[nt2]);
            }
        }
    }

#pragma unroll
    for (int reg = 0; reg < 4; ++reg) {
        float inv = 1.f / l_i[reg];
        size_t orow = rowbase + (size_t)(q0 + w * 16 + quad * 4 + reg) * DM;
#pragma unroll
        for (int nt2 = 0; nt2 < 8; ++nt2)
            O[orow + nt2 * 16 + col] = f2bf(o[nt2][reg] * inv);
    }
}

extern "C" void kernel_launch(void* const* d_in, const int* in_sizes, int n_in,
                              void* d_out, int out_size, void* d_ws, size_t ws_size,
                              hipStream_t stream) {
    const float* x    = (const float*)d_in[0];
    // d_in[1] = mask (unused; causal structure is known)
    const float* cosp = (const float*)d_in[2];
    const float* sinp = (const float*)d_in[3];
    const float* Wq   = (const float*)d_in[4];
    const float* Wk   = (const float*)d_in[5];
    const float* Wv   = (const float*)d_in[6];
    const float* Wo   = (const float*)d_in[7];
    float* out = (float*)d_out;

    unsigned short* xb  = (unsigned short*)d_ws;             // 4096*2048
    unsigned short* wtq = xb  + (size_t)NROW * DM;           // 2048*2048 each
    unsigned short* wtk = wtq + (size_t)DM * DM;
    unsigned short* wtv = wtk + (size_t)DM * DM;
    unsigned short* wto = wtv + (size_t)DM * DM;
    unsigned short* qb  = wto + (size_t)DM * DM;             // 4096*2048 each
    unsigned short* kb  = qb  + (size_t)NROW * DM;
    unsigned short* vb  = kb  + (size_t)NROW * DM;
    unsigned short* ob  = vb  + (size_t)NROW * DM;

    hipLaunchKernelGGL(k_cast, dim3(8192), dim3(256), 0, stream, x, xb, NROW * DM);
    hipLaunchKernelGGL(k_transpose, dim3(64, 64, 4), dim3(32, 8), 0, stream,
                       Wq, Wk, Wv, Wo, wtq, wtk, wtv, wto);
    hipLaunchKernelGGL(k_gemm_qkv, dim3(16, 32, 3), dim3(256), 0, stream,
                       xb, wtq, wtk, wtv, qb, kb, vb);
    hipLaunchKernelGGL(k_rope, dim3(16384), dim3(256), 0, stream, qb, kb, cosp, sinp);
    hipLaunchKernelGGL(k_flash, dim3(32, NH, 2), dim3(256), 0, stream, qb, kb, vb, ob);
    hipLaunchKernelGGL(k_gemm_out, dim3(16, 32, 1), dim3(256), 0, stream, ob, wto, out);
}

// Round 2
// 458.905 us; speedup vs baseline: 1.1150x; 1.1150x over previous
//
#include <hip/hip_runtime.h>

#define T_SEQ 2048
#define DM    2048
#define NH    16
#define HD    128
#define NROW  4096   // B*T

typedef __attribute__((ext_vector_type(8))) short short8;
typedef __attribute__((ext_vector_type(4))) float f32x4;

static __device__ __forceinline__ float bf2f(unsigned short h) {
    unsigned int u = ((unsigned int)h) << 16;
    return __builtin_bit_cast(float, u);
}
static __device__ __forceinline__ unsigned short f2bf(float f) {
    unsigned int u = __builtin_bit_cast(unsigned int, f);
    u += 0x7FFFu + ((u >> 16) & 1u);
    return (unsigned short)(u >> 16);
}
// cheap round-half-up bf16 (2 VALU ops) for P/O inner-loop conversions
static __device__ __forceinline__ unsigned short bf_fast(float f) {
    return (unsigned short)((__builtin_bit_cast(unsigned int, f) + 0x8000u) >> 16);
}

typedef __attribute__((address_space(1))) const unsigned int gas_uint;
typedef __attribute__((address_space(3))) unsigned int las_uint;

static __device__ __forceinline__ void load_lds16(const void* g, void* l) {
    __builtin_amdgcn_global_load_lds((gas_uint*)g, (las_uint*)l, 16, 0, 0);
}

static __device__ __forceinline__ f32x4 mfma_bf16(short8 a, short8 b, f32x4 c) {
    return __builtin_amdgcn_mfma_f32_16x16x32_bf16(a, b, c, 0, 0, 0);
}

// ---------------- cast x -> bf16 ----------------
__global__ __launch_bounds__(256) void k_cast(const float* __restrict__ x,
                                              unsigned short* __restrict__ xb, int n) {
    int idx = (blockIdx.x * 256 + threadIdx.x) * 4;
    if (idx >= n) return;
    float4 v = *(const float4*)(x + idx);
    ushort4 o;
    o.x = f2bf(v.x); o.y = f2bf(v.y); o.z = f2bf(v.z); o.w = f2bf(v.w);
    *(ushort4*)(xb + idx) = o;
}

// ---------------- transpose+cast weights: W[k][n] f32 -> Wt[n][k] bf16 ----------------
__global__ __launch_bounds__(256) void k_transpose(const float* __restrict__ w0, const float* __restrict__ w1,
                                                   const float* __restrict__ w2, const float* __restrict__ w3,
                                                   unsigned short* __restrict__ t0, unsigned short* __restrict__ t1,
                                                   unsigned short* __restrict__ t2, unsigned short* __restrict__ t3) {
    __shared__ float tile[32][33];
    int z = blockIdx.z;
    const float* W = (z == 0) ? w0 : (z == 1) ? w1 : (z == 2) ? w2 : w3;
    unsigned short* Wt = (z == 0) ? t0 : (z == 1) ? t1 : (z == 2) ? t2 : t3;
    int bx = blockIdx.x * 32;  // n base
    int by = blockIdx.y * 32;  // k base
    int tx = threadIdx.x, ty = threadIdx.y;
#pragma unroll
    for (int i = 0; i < 4; ++i)
        tile[ty + i * 8][tx] = W[(size_t)(by + ty + i * 8) * DM + bx + tx];
    __syncthreads();
#pragma unroll
    for (int i = 0; i < 4; ++i)
        Wt[(size_t)(bx + ty + i * 8) * DM + by + tx] = f2bf(tile[tx][ty + i * 8]);
}

// ---------------- 128x128 GEMM, A[M][K] bf16 @ Bt[N][K] bf16 -> C[M][N] ----------------
template <bool FOUT>
static __device__ __forceinline__ void gemm_body(const unsigned short* __restrict__ A,
                                                 const unsigned short* __restrict__ Bt,
                                                 unsigned short* __restrict__ Cb,
                                                 float* __restrict__ Cf) {
    __shared__ unsigned short As[128 * 64];
    __shared__ unsigned short Bs[128 * 64];
    const int tid = threadIdx.x;
    const int w = tid >> 6, lane = tid & 63;
    const int col = lane & 15, quad = lane >> 4;
    const int wm = w >> 1, wn = w & 1;
    const size_t m0 = (size_t)blockIdx.y * 128;
    const size_t n0 = (size_t)blockIdx.x * 128;

    f32x4 acc[4][4];
#pragma unroll
    for (int i = 0; i < 4; ++i)
#pragma unroll
        for (int j = 0; j < 4; ++j)
            acc[i][j] = (f32x4){0.f, 0.f, 0.f, 0.f};

    const int lrow = lane >> 3;                 // 0..7 row within 8-row chunk
    const int gcol = ((lane & 7) ^ lrow) * 8;   // XOR-swizzled logical col (elems)

    for (int k0 = 0; k0 < DM; k0 += 64) {
#pragma unroll
        for (int c = w; c < 16; c += 4) {
            load_lds16(A + (m0 + c * 8 + lrow) * DM + k0 + gcol, &As[c * 512]);
            load_lds16(Bt + (n0 + c * 8 + lrow) * DM + k0 + gcol, &Bs[c * 512]);
        }
        __syncthreads();
#pragma unroll
        for (int ks = 0; ks < 2; ++ks) {
            short8 af[4], bf[4];
            int g = ks * 4 + quad;
#pragma unroll
            for (int mt = 0; mt < 4; ++mt) {
                int r = wm * 64 + mt * 16 + col;
                af[mt] = *(const short8*)&As[r * 64 + ((g ^ (r & 7)) * 8)];
            }
#pragma unroll
            for (int nt = 0; nt < 4; ++nt) {
                int r = wn * 64 + nt * 16 + col;
                bf[nt] = *(const short8*)&Bs[r * 64 + ((g ^ (r & 7)) * 8)];
            }
#pragma unroll
            for (int mt = 0; mt < 4; ++mt)
#pragma unroll
                for (int nt = 0; nt < 4; ++nt)
                    acc[mt][nt] = mfma_bf16(af[mt], bf[nt], acc[mt][nt]);
        }
        __syncthreads();
    }
#pragma unroll
    for (int mt = 0; mt < 4; ++mt)
#pragma unroll
        for (int nt = 0; nt < 4; ++nt)
#pragma unroll
            for (int reg = 0; reg < 4; ++reg) {
                size_t r = m0 + wm * 64 + mt * 16 + quad * 4 + reg;
                size_t c = n0 + wn * 64 + nt * 16 + col;
                if (FOUT) Cf[r * DM + c] = acc[mt][nt][reg];
                else      Cb[r * DM + c] = f2bf(acc[mt][nt][reg]);
            }
}

__global__ __launch_bounds__(256) void k_gemm_qkv(const unsigned short* __restrict__ xb,
                                                  const unsigned short* __restrict__ wtq,
                                                  const unsigned short* __restrict__ wtk,
                                                  const unsigned short* __restrict__ wtv,
                                                  unsigned short* __restrict__ qb,
                                                  unsigned short* __restrict__ kb,
                                                  unsigned short* __restrict__ vb) {
    int z = blockIdx.z;
    const unsigned short* Bt = (z == 0) ? wtq : (z == 1) ? wtk : wtv;
    unsigned short* C = (z == 0) ? qb : (z == 1) ? kb : vb;
    gemm_body<false>(xb, Bt, C, nullptr);
}

__global__ __launch_bounds__(256) void k_gemm_out(const unsigned short* __restrict__ ob,
                                                  const unsigned short* __restrict__ wto,
                                                  float* __restrict__ out) {
    gemm_body<true>(ob, wto, nullptr, out);
}

// ---------------- RoPE in place on K only (Q is roped in-register in k_flash) ----------------
__global__ __launch_bounds__(256) void k_rope_k(unsigned short* __restrict__ K,
                                                const float* __restrict__ cosp,
                                                const float* __restrict__ sinp) {
    int idx = blockIdx.x * 256 + threadIdx.x;   // NROW*16*16 threads
    int d4 = (idx & 15) * 4;
    int h = (idx >> 4) & 15;
    int row = idx >> 8;
    int t = row & (T_SEQ - 1);
    size_t base = (size_t)row * DM + h * HD + d4;
    ushort4 x1 = *(const ushort4*)(K + base);
    ushort4 x2 = *(const ushort4*)(K + base + 64);
    float4 c = *(const float4*)(cosp + t * 64 + d4);
    float4 s = *(const float4*)(sinp + t * 64 + d4);
    ushort4 o1, o2;
#pragma unroll
    for (int i = 0; i < 4; ++i) {
        float a1 = bf2f(((const unsigned short*)&x1)[i]);
        float a2 = bf2f(((const unsigned short*)&x2)[i]);
        float cc = ((const float*)&c)[i], ss = ((const float*)&s)[i];
        ((unsigned short*)&o1)[i] = f2bf(a1 * cc - a2 * ss);
        ((unsigned short*)&o2)[i] = f2bf(a1 * ss + a2 * cc);
    }
    *(ushort4*)(K + base) = o1;
    *(ushort4*)(K + base + 64) = o2;
}

// ---------------- V transpose: vb[b*T+t][h*128+d] -> Vt[(b*16+h)*128+d][t] ----------------
__global__ __launch_bounds__(256) void k_vtr(const unsigned short* __restrict__ V,
                                             unsigned short* __restrict__ Vt) {
    __shared__ unsigned short tile[64][68];
    int t0 = blockIdx.x * 64;
    int hd0 = blockIdx.y * 64;
    int b = blockIdx.z;
    int tid = threadIdx.x;
    int rr = tid >> 4, cc = (tid & 15) * 4;
#pragma unroll
    for (int it = 0; it < 4; ++it) {
        int row = it * 16 + rr;
        *(ushort4*)&tile[row][cc] =
            *(const ushort4*)(V + (size_t)(b * T_SEQ + t0 + row) * DM + hd0 + cc);
    }
    __syncthreads();
    int h = hd0 >> 7, d0 = hd0 & 127;
    size_t obase = (size_t)(b * NH + h) * HD;
#pragma unroll
    for (int it = 0; it < 4; ++it) {
        int lhd = it * 16 + rr;
        ushort4 v;
#pragma unroll
        for (int j = 0; j < 4; ++j) ((unsigned short*)&v)[j] = tile[cc + j][lhd];
        *(ushort4*)(Vt + (obase + d0 + lhd) * (size_t)T_SEQ + t0 + cc) = v;
    }
}

// ---------------- causal flash attention, paired q-tiles for balance ----------------
// grid (16, H, B), block 256 (4 waves). Block bx handles q-tiles bx and 31-bx.
__global__ __launch_bounds__(256) void k_flash(const unsigned short* __restrict__ Q,
                                               const unsigned short* __restrict__ K,
                                               const unsigned short* __restrict__ Vt,
                                               unsigned short* __restrict__ O,
                                               const float* __restrict__ cosp,
                                               const float* __restrict__ sinp) {
    __shared__ unsigned short Ks[64 * 128];
    __shared__ unsigned short Vs[128 * 64];
    __shared__ unsigned short Ps[4 * 16 * 72];
    const int tid = threadIdx.x;
    const int w = tid >> 6, lane = tid & 63;
    const int col = lane & 15, quad = lane >> 4;
    const int h = blockIdx.y, b = blockIdx.z;
    const int txlo = blockIdx.x;        // 0..15
    const int txhi = 31 - txlo;         // 16..31
    const int q0lo = txlo * 64, q0hi = txhi * 64;
    const size_t rowbase = ((size_t)b * T_SEQ) * DM + (size_t)h * HD;
    const size_t hbase = ((size_t)b * NH + h) * HD;
    const float SCL = 0.088388347648318447f * 1.4426950408889634f;  // 1/sqrt(D) * log2(e)

    // ---- load Q fragments + in-register RoPE (scale folded into cos/sin) ----
    short8 qlo[4], qhi[4];
    auto load_q = [&](int q0, short8* qf) {
        const int t = q0 + w * 16 + col;
        const unsigned short* qp = Q + rowbase + (size_t)t * DM;
#pragma unroll
        for (int ks = 0; ks < 4; ++ks)
            qf[ks] = *(const short8*)(qp + ks * 32 + quad * 8);
        const float* cp = cosp + t * 64 + quad * 8;
        const float* sp = sinp + t * 64 + quad * 8;
#pragma unroll
        for (int ks = 0; ks < 2; ++ks) {
            float4 c0 = *(const float4*)(cp + ks * 32);
            float4 c1 = *(const float4*)(cp + ks * 32 + 4);
            float4 s0 = *(const float4*)(sp + ks * 32);
            float4 s1 = *(const float4*)(sp + ks * 32 + 4);
#pragma unroll
            for (int j = 0; j < 8; ++j) {
                float cv = ((j < 4) ? ((const float*)&c0)[j] : ((const float*)&c1)[j - 4]) * SCL;
                float sv = ((j < 4) ? ((const float*)&s0)[j] : ((const float*)&s1)[j - 4]) * SCL;
                float a1 = bf2f((unsigned short)qf[ks][j]);
                float a2 = bf2f((unsigned short)qf[ks + 2][j]);
                qf[ks][j]     = (short)f2bf(a1 * cv - a2 * sv);
                qf[ks + 2][j] = (short)f2bf(a1 * sv + a2 * cv);
            }
        }
    };
    load_q(q0lo, qlo);
    load_q(q0hi, qhi);

    f32x4 olo[8], ohi[8];
    float mlo[4], llo[4], mhi[4], lhi[4];
#pragma unroll
    for (int i = 0; i < 8; ++i) {
        olo[i] = (f32x4){0.f, 0.f, 0.f, 0.f};
        ohi[i] = (f32x4){0.f, 0.f, 0.f, 0.f};
    }
#pragma unroll
    for (int r = 0; r < 4; ++r) {
        mlo[r] = -1e30f; llo[r] = 0.f;
        mhi[r] = -1e30f; lhi[r] = 0.f;
    }

    auto tile_step = [&](const short8* qf, f32x4* o, float* m_i, float* l_i,
                         bool diag, int q0t, int k0) {
        f32x4 s[4];
#pragma unroll
        for (int i = 0; i < 4; ++i) s[i] = (f32x4){0.f, 0.f, 0.f, 0.f};
#pragma unroll
        for (int ks = 0; ks < 4; ++ks) {
            const int g = ks * 4 + quad;
#pragma unroll
            for (int nt = 0; nt < 4; ++nt) {
                const int key = nt * 16 + col;
                short8 bfr = *(const short8*)&Ks[key * 128 + ((g ^ (key & 7)) * 8)];
                s[nt] = mfma_bf16(qf[ks], bfr, s[nt]);
            }
        }
        if (diag) {
#pragma unroll
            for (int nt = 0; nt < 4; ++nt)
#pragma unroll
                for (int reg = 0; reg < 4; ++reg)
                    if (k0 + nt * 16 + col > q0t + w * 16 + quad * 4 + reg)
                        s[nt][reg] = -1e30f;
        }
        float alpha[4];
#pragma unroll
        for (int reg = 0; reg < 4; ++reg) {
            float mx = fmaxf(fmaxf(s[0][reg], s[1][reg]), fmaxf(s[2][reg], s[3][reg]));
            mx = fmaxf(mx, __shfl_xor(mx, 1));
            mx = fmaxf(mx, __shfl_xor(mx, 2));
            mx = fmaxf(mx, __shfl_xor(mx, 4));
            mx = fmaxf(mx, __shfl_xor(mx, 8));
            float mnew = fmaxf(m_i[reg], mx);
            alpha[reg] = __builtin_amdgcn_exp2f(m_i[reg] - mnew);
            m_i[reg] = mnew;
            float sum = 0.f;
            const int prow = w * 16 + quad * 4 + reg;
#pragma unroll
            for (int nt = 0; nt < 4; ++nt) {
                float p = __builtin_amdgcn_exp2f(s[nt][reg] - mnew);
                sum += p;
                Ps[prow * 72 + nt * 16 + col] = bf_fast(p);
            }
            sum += __shfl_xor(sum, 1);
            sum += __shfl_xor(sum, 2);
            sum += __shfl_xor(sum, 4);
            sum += __shfl_xor(sum, 8);
            l_i[reg] = l_i[reg] * alpha[reg] + sum;
        }
        f32x4 av = {alpha[0], alpha[1], alpha[2], alpha[3]};
#pragma unroll
        for (int nt2 = 0; nt2 < 8; ++nt2) o[nt2] *= av;
#pragma unroll
        for (int ks2 = 0; ks2 < 2; ++ks2) {
            short8 a = *(const short8*)&Ps[(w * 16 + col) * 72 + ks2 * 32 + quad * 8];
            const int g = ks2 * 4 + quad;
#pragma unroll
            for (int nt2 = 0; nt2 < 8; ++nt2) {
                const int d = nt2 * 16 + col;
                short8 bfr = *(const short8*)&Vs[d * 64 + ((g ^ (d & 7)) * 8)];
                o[nt2] = mfma_bf16(a, bfr, o[nt2]);
            }
        }
    };

    for (int kt = 0; kt <= txhi; ++kt) {
        const int k0 = kt * 64;
        __syncthreads();
        // stage K tile [64 keys][128 d] (4 rows per call) and V tile [128 d][64 keys]
#pragma unroll
        for (int c = 0; c < 4; ++c) {
            const int c4 = w * 4 + c;
            const int krow = c4 * 4 + (lane >> 4);
            const int kpos = lane & 15;
            load_lds16(K + rowbase + (size_t)(k0 + krow) * DM + ((kpos ^ (krow & 7)) * 8),
                       &Ks[c4 * 512]);
            const int vrow = c4 * 8 + (lane >> 3);
            const int vpos = lane & 7;
            load_lds16(Vt + (hbase + vrow) * (size_t)T_SEQ + k0 + ((vpos ^ (vrow & 7)) * 8),
                       &Vs[c4 * 512]);
        }
        __syncthreads();
        tile_step(qhi, ohi, mhi, lhi, kt == txhi, q0hi, k0);
        if (kt <= txlo)
            tile_step(qlo, olo, mlo, llo, kt == txlo, q0lo, k0);
    }

    auto finish = [&](const f32x4* o, const float* l_i, int q0t) {
#pragma unroll
        for (int reg = 0; reg < 4; ++reg) {
            float inv = __builtin_amdgcn_rcpf(l_i[reg]);
            unsigned short* op = O + rowbase + (size_t)(q0t + w * 16 + quad * 4 + reg) * DM;
#pragma unroll
            for (int nt2 = 0; nt2 < 8; ++nt2)
                op[nt2 * 16 + col] = bf_fast(o[nt2][reg] * inv);
        }
    };
    finish(olo, llo, q0lo);
    finish(ohi, lhi, q0hi);
}

extern "C" void kernel_launch(void* const* d_in, const int* in_sizes, int n_in,
                              void* d_out, int out_size, void* d_ws, size_t ws_size,
                              hipStream_t stream) {
    const float* x    = (const float*)d_in[0];
    // d_in[1] = mask (unused; causal structure is known)
    const float* cosp = (const float*)d_in[2];
    const float* sinp = (const float*)d_in[3];
    const float* Wq   = (const float*)d_in[4];
    const float* Wk   = (const float*)d_in[5];
    const float* Wv   = (const float*)d_in[6];
    const float* Wo   = (const float*)d_in[7];
    float* out = (float*)d_out;

    unsigned short* xb  = (unsigned short*)d_ws;             // 4096*2048 (reused as Vt later)
    unsigned short* wtq = xb  + (size_t)NROW * DM;           // 2048*2048 each
    unsigned short* wtk = wtq + (size_t)DM * DM;
    unsigned short* wtv = wtk + (size_t)DM * DM;
    unsigned short* wto = wtv + (size_t)DM * DM;
    unsigned short* qb  = wto + (size_t)DM * DM;             // 4096*2048 each
    unsigned short* kb  = qb  + (size_t)NROW * DM;
    unsigned short* vb  = kb  + (size_t)NROW * DM;
    unsigned short* ob  = vb  + (size_t)NROW * DM;
    unsigned short* vt  = xb;  // xb is dead after k_gemm_qkv; reuse for transposed V

    hipLaunchKernelGGL(k_cast, dim3(8192), dim3(256), 0, stream, x, xb, NROW * DM);
    hipLaunchKernelGGL(k_transpose, dim3(64, 64, 4), dim3(32, 8), 0, stream,
                       Wq, Wk, Wv, Wo, wtq, wtk, wtv, wto);
    hipLaunchKernelGGL(k_gemm_qkv, dim3(16, 32, 3), dim3(256), 0, stream,
                       xb, wtq, wtk, wtv, qb, kb, vb);
    hipLaunchKernelGGL(k_rope_k, dim3(4096), dim3(256), 0, stream, kb, cosp, sinp);
    hipLaunchKernelGGL(k_vtr, dim3(32, 32, 2), dim3(256), 0, stream, vb, vt);
    hipLaunchKernelGGL(k_flash, dim3(16, NH, 2), dim3(256), 0, stream,
                       qb, kb, vt, ob, cosp, sinp);
    hipLaunchKernelGGL(k_gemm_out, dim3(16, 32, 1), dim3(256), 0, stream, ob, wto, out);
}